// Round 2
// baseline (849.955 us; speedup 1.0000x reference)
//
#include <hip/hip_runtime.h>
#include <hip/hip_bf16.h>

// 3-layer GCN, N=100000, E=1.6M, D=64.
// Restructure: LN(Agg(h) @ W + b) per layer (aggregation commutes with @W).
// Pipeline: detect dtype -> CSR build -> normalize to bf16 -> 3x (aggregate, gemm_ln).
// Workspace peak ~33 MB (CSR temporaries aliased into AG region).

#define DDIM 64
#define EPSV 1e-5f

typedef __hip_bfloat16 bf16;
typedef unsigned int u32;
typedef unsigned short u16;

__device__ __forceinline__ float b2f(bf16 v) { return __bfloat162float(v); }
__device__ __forceinline__ float bits2f(u16 b) {
    union { u32 u; float f; } c; c.u = ((u32)b) << 16; return c.f;
}

// ---- dtype detect: gammas are all ones; word0 = 0x3F803F80 (bf16) or 0x3F800000 (f32)
__global__ void detect_dtype(const u32* __restrict__ g, int* __restrict__ flagF32) {
    if (threadIdx.x == 0 && blockIdx.x == 0) *flagF32 = (g[0] == 0x3F800000u) ? 1 : 0;
}

__global__ void convert_to_bf16(const void* __restrict__ src, bf16* __restrict__ dst,
                                const int* __restrict__ flagF32, int n) {
    int i = blockIdx.x * blockDim.x + threadIdx.x;
    if (i >= n) return;
    float v = (*flagF32) ? ((const float*)src)[i] : b2f(((const bf16*)src)[i]);
    dst[i] = __float2bfloat16(v);
}

// ---- CSR build -------------------------------------------------------------

__global__ void count_deg(const int* __restrict__ col, int* __restrict__ cnt, int E) {
    int e = blockIdx.x * blockDim.x + threadIdx.x;
    if (e < E) atomicAdd(&cnt[col[e]], 1);
}

__global__ void scan_block(const int* __restrict__ cnt, int* __restrict__ incl,
                           int* __restrict__ bsum, int N) {
    __shared__ int s[1024];
    int tid = threadIdx.x;
    int i = blockIdx.x * 1024 + tid;
    int v = (i < N) ? cnt[i] : 0;
    s[tid] = v;
    __syncthreads();
    for (int off = 1; off < 1024; off <<= 1) {
        int t = (tid >= off) ? s[tid - off] : 0;
        __syncthreads();
        s[tid] += t;
        __syncthreads();
    }
    if (i < N) incl[i] = s[tid];
    if (tid == 1023) bsum[blockIdx.x] = s[1023];
}

__global__ void scan_partials(const int* __restrict__ bsum, int* __restrict__ boff, int nb) {
    __shared__ int s[1024];
    int tid = threadIdx.x;
    int v = (tid < nb) ? bsum[tid] : 0;
    s[tid] = v;
    __syncthreads();
    for (int off = 1; off < 1024; off <<= 1) {
        int t = (tid >= off) ? s[tid - off] : 0;
        __syncthreads();
        s[tid] += t;
        __syncthreads();
    }
    if (tid < nb) boff[tid] = s[tid] - v;  // exclusive
}

__global__ void finalize_csr(const int* __restrict__ cnt, const int* __restrict__ incl,
                             const int* __restrict__ boff, int* __restrict__ ptr,
                             int* __restrict__ fill, float* __restrict__ dinv, int N) {
    int i = blockIdx.x * blockDim.x + threadIdx.x;
    if (i >= N) return;
    int excl = incl[i] - cnt[i] + boff[i >> 10];
    ptr[i] = excl;
    fill[i] = excl;
    dinv[i] = rsqrtf((float)(cnt[i] + 1));  // +1 self loop -> deg>0 always
    if (i == N - 1) ptr[N] = excl + cnt[i];
}

__global__ void fill_csr(const int* __restrict__ row, const int* __restrict__ col,
                         int* __restrict__ fill, int* __restrict__ srcs, int E) {
    int e = blockIdx.x * blockDim.x + threadIdx.x;
    if (e >= E) return;
    int p = atomicAdd(&fill[col[e]], 1);
    srcs[p] = row[e];
}

// ---- Aggregation: AG[v] = dinv[v]*( dinv[v]*H[v] + sum_e dinv[src]*H[src] ) -
// One wave per node, lane = feature.

__global__ void __launch_bounds__(256) aggregate(const bf16* __restrict__ Hin,
                                                 const int* __restrict__ ptr,
                                                 const int* __restrict__ srcs,
                                                 const float* __restrict__ dinv,
                                                 bf16* __restrict__ AG, int N) {
    int t = blockIdx.x * blockDim.x + threadIdx.x;
    int v = t >> 6;
    int lane = t & 63;
    if (v >= N) return;
    float dv = dinv[v];
    float acc = dv * b2f(Hin[(size_t)v * DDIM + lane]);  // self loop (x dv again below)
    int beg = ptr[v], end = ptr[v + 1];
    for (int i = beg; i < end; i++) {
        int s = srcs[i];
        acc += dinv[s] * b2f(Hin[(size_t)s * DDIM + lane]);
    }
    AG[(size_t)v * DDIM + lane] = __float2bfloat16(dv * acc);
}

// ---- Fused GEMM (AG @ W + b) + LayerNorm (+ReLU) ---------------------------
// One block = 16 rows; one wave = 4 rows x 64 cols (lane = col).

__global__ void __launch_bounds__(256) gemm_ln(const bf16* __restrict__ AG,
                                               const bf16* __restrict__ W,
                                               const bf16* __restrict__ bias,
                                               const bf16* __restrict__ gamma,
                                               const bf16* __restrict__ beta,
                                               bf16* __restrict__ outB,
                                               float* __restrict__ outF,
                                               const int* __restrict__ flagF32,
                                               int relu, int last) {
    __shared__ float Ws[4096];  // W[k][j] row-major, 16 KB
    __shared__ float As[1024];  // 16 rows x 64
    int tid = threadIdx.x;
    const ushort4* wp = (const ushort4*)W;  // 4096 bf16 = 1024 x ushort4
    for (int i = tid; i < 1024; i += 256) {
        ushort4 u = wp[i];
        Ws[i * 4 + 0] = bits2f(u.x);
        Ws[i * 4 + 1] = bits2f(u.y);
        Ws[i * 4 + 2] = bits2f(u.z);
        Ws[i * 4 + 3] = bits2f(u.w);
    }
    {
        const ushort4* ap = (const ushort4*)(AG + (size_t)blockIdx.x * 1024);
        ushort4 u = ap[tid];  // 256 threads x 4 = 1024 elements
        As[tid * 4 + 0] = bits2f(u.x);
        As[tid * 4 + 1] = bits2f(u.y);
        As[tid * 4 + 2] = bits2f(u.z);
        As[tid * 4 + 3] = bits2f(u.w);
    }
    __syncthreads();

    int lane = tid & 63;
    int wv = tid >> 6;
    int l0 = wv * 4;
    float a0 = 0.f, a1 = 0.f, a2 = 0.f, a3 = 0.f;
#pragma unroll 8
    for (int k = 0; k < 64; k++) {
        float w = Ws[k * 64 + lane];      // 2 lanes/bank: free
        a0 += As[(l0 + 0) * 64 + k] * w;  // broadcast
        a1 += As[(l0 + 1) * 64 + k] * w;
        a2 += As[(l0 + 2) * 64 + k] * w;
        a3 += As[(l0 + 3) * 64 + k] * w;
    }
    float bb = b2f(bias[lane]);
    float gg = b2f(gamma[lane]);
    float be = b2f(beta[lane]);
    int f32o = last ? flagF32[0] : 0;  // wave-uniform
    size_t n0 = (size_t)blockIdx.x * 16 + l0;
    float accs[4] = {a0, a1, a2, a3};
#pragma unroll
    for (int i = 0; i < 4; i++) {
        float vv = accs[i] + bb;
        float sum = vv;
#pragma unroll
        for (int m = 1; m < 64; m <<= 1) sum += __shfl_xor(sum, m, 64);
        float mu = sum * (1.f / 64.f);
        float d = vv - mu;
        float sq = d * d;
#pragma unroll
        for (int m = 1; m < 64; m <<= 1) sq += __shfl_xor(sq, m, 64);
        float var = sq * (1.f / 64.f);
        float o = d * rsqrtf(var + EPSV) * gg + be;
        if (relu) o = fmaxf(o, 0.f);
        size_t idx = (n0 + i) * DDIM + lane;
        if (f32o) outF[idx] = o;
        else      outB[idx] = __float2bfloat16(o);
    }
}

// ---- Launch ----------------------------------------------------------------

extern "C" void kernel_launch(void* const* d_in, const int* in_sizes, int n_in,
                              void* d_out, int out_size, void* d_ws, size_t ws_size,
                              hipStream_t stream) {
    (void)n_in; (void)out_size; (void)ws_size;
    const void* x      = d_in[0];
    const void* Wsrc   = d_in[1];
    const void* bsrc   = d_in[2];
    const void* gsrc   = d_in[3];
    const void* btsrc  = d_in[4];
    const int*  ei     = (const int*)d_in[5];
    int N = in_sizes[0] / DDIM;   // 100000
    int E = in_sizes[5] / 2;      // 1600000
    const int* rowp = ei;         // sources (gather)
    const int* colp = ei + E;     // targets (scatter)

    // workspace carve-out (256B aligned); peak ~33 MB
    char* w = (char*)d_ws;
    auto alloc = [&](size_t bytes) -> char* {
        char* p = w;
        w += (bytes + 255) / 256 * 256;
        return p;
    };
    int*   flag = (int*)alloc(4);
    int*   ptr  = (int*)alloc((size_t)(N + 1) * 4);
    int*   srcs = (int*)alloc((size_t)E * 4);
    float* dinv = (float*)alloc((size_t)N * 4);
    bf16*  H    = (bf16*)alloc((size_t)N * DDIM * 2);
    bf16*  wsW  = (bf16*)alloc((size_t)3 * 4096 * 2);
    bf16*  wsB  = (bf16*)alloc(192 * 2);
    bf16*  wsG  = (bf16*)alloc(192 * 2);
    bf16*  wsBt = (bf16*)alloc(192 * 2);
    char*  agreg = alloc((size_t)N * DDIM * 2);
    bf16*  AG   = (bf16*)agreg;
    // CSR-build temporaries aliased into AG region (dead before AG is written)
    int*   cnt  = (int*)agreg;
    int*   incl = cnt + N;
    int*   fill = incl + N;
    int*   bsum = fill + N;
    int*   boff = bsum + 1024;

    const int tb = 256;
    detect_dtype<<<1, 64, 0, stream>>>((const u32*)gsrc, flag);
    hipMemsetAsync(cnt, 0, (size_t)N * 4, stream);
    count_deg<<<(E + tb - 1) / tb, tb, 0, stream>>>(colp, cnt, E);
    int nb = (N + 1023) / 1024;  // 98
    scan_block<<<nb, 1024, 0, stream>>>(cnt, incl, bsum, N);
    scan_partials<<<1, 1024, 0, stream>>>(bsum, boff, nb);
    finalize_csr<<<(N + tb - 1) / tb, tb, 0, stream>>>(cnt, incl, boff, ptr, fill, dinv, N);
    fill_csr<<<(E + tb - 1) / tb, tb, 0, stream>>>(rowp, colp, fill, srcs, E);

    // normalize inputs to bf16 (no-op copy if already bf16)
    convert_to_bf16<<<(N * DDIM + tb - 1) / tb, tb, 0, stream>>>(x, H, flag, N * DDIM);
    convert_to_bf16<<<(3 * 4096 + tb - 1) / tb, tb, 0, stream>>>(Wsrc, wsW, flag, 3 * 4096);
    convert_to_bf16<<<1, 192, 0, stream>>>(bsrc, wsB, flag, 192);
    convert_to_bf16<<<1, 192, 0, stream>>>(gsrc, wsG, flag, 192);
    convert_to_bf16<<<1, 192, 0, stream>>>(btsrc, wsBt, flag, 192);

    int aggBlocks = (N * DDIM + tb - 1) / tb;  // one wave per node
    int gBlocks = N / 16;                      // 6250

    aggregate<<<aggBlocks, tb, 0, stream>>>(H, ptr, srcs, dinv, AG, N);
    gemm_ln<<<gBlocks, tb, 0, stream>>>(AG, wsW + 0 * 4096, wsB + 0,   wsG + 0,   wsBt + 0,   H, nullptr, flag, 1, 0);
    aggregate<<<aggBlocks, tb, 0, stream>>>(H, ptr, srcs, dinv, AG, N);
    gemm_ln<<<gBlocks, tb, 0, stream>>>(AG, wsW + 1 * 4096, wsB + 64,  wsG + 64,  wsBt + 64,  H, nullptr, flag, 1, 0);
    aggregate<<<aggBlocks, tb, 0, stream>>>(H, ptr, srcs, dinv, AG, N);
    gemm_ln<<<gBlocks, tb, 0, stream>>>(AG, wsW + 2 * 4096, wsB + 128, wsG + 128, wsBt + 128,
                                        (bf16*)d_out, (float*)d_out, flag, 0, 1);
}

// Round 3
// 581.667 us; speedup vs baseline: 1.4612x; 1.4612x over previous
//
#include <hip/hip_runtime.h>
#include <hip/hip_bf16.h>

// 3-layer GCN, N=100000, E=1.6M, D=64.
// Restructure: LN(Agg(h) @ W + b) per layer (aggregation commutes with @W).
// Pipeline: detect dtype -> CSR build -> normalize to bf16 -> 3x (aggregate, gemm_ln).
// aggregate v2: chunked coalesced index loads + shfl distribution + 8-wide
// independent row gathers (MLP) instead of serial per-edge broadcast loads.

#define DDIM 64
#define EPSV 1e-5f

typedef __hip_bfloat16 bf16;
typedef unsigned int u32;
typedef unsigned short u16;

__device__ __forceinline__ float b2f(bf16 v) { return __bfloat162float(v); }
__device__ __forceinline__ float bits2f(u16 b) {
    union { u32 u; float f; } c; c.u = ((u32)b) << 16; return c.f;
}
__device__ __forceinline__ float cvt_load(const void* src, int i, int f32) {
    return f32 ? ((const float*)src)[i] : b2f(((const bf16*)src)[i]);
}

// ---- dtype detect: gammas are all ones; word0 = 0x3F803F80 (bf16) or 0x3F800000 (f32)
__global__ void detect_dtype(const u32* __restrict__ g, int* __restrict__ flagF32) {
    if (threadIdx.x == 0 && blockIdx.x == 0) *flagF32 = (g[0] == 0x3F800000u) ? 1 : 0;
}

__global__ void convert_to_bf16(const void* __restrict__ src, bf16* __restrict__ dst,
                                const int* __restrict__ flagF32, int n) {
    int i = blockIdx.x * blockDim.x + threadIdx.x;
    if (i >= n) return;
    dst[i] = __float2bfloat16(cvt_load(src, i, *flagF32));
}

__global__ void convert_params(const void* __restrict__ W, const void* __restrict__ b,
                               const void* __restrict__ g, const void* __restrict__ bt,
                               bf16* __restrict__ dW, bf16* __restrict__ db,
                               bf16* __restrict__ dg, bf16* __restrict__ dbt,
                               const int* __restrict__ flagF32, int nW, int nS) {
    int i = blockIdx.x * blockDim.x + threadIdx.x;
    int f = *flagF32;
    if (i < nW) { dW[i] = __float2bfloat16(cvt_load(W, i, f)); return; }
    i -= nW;
    if (i < nS) { db[i] = __float2bfloat16(cvt_load(b, i, f)); return; }
    i -= nS;
    if (i < nS) { dg[i] = __float2bfloat16(cvt_load(g, i, f)); return; }
    i -= nS;
    if (i < nS) { dbt[i] = __float2bfloat16(cvt_load(bt, i, f)); }
}

// ---- CSR build -------------------------------------------------------------

__global__ void count_deg(const int* __restrict__ col, int* __restrict__ cnt, int E) {
    int e = blockIdx.x * blockDim.x + threadIdx.x;
    if (e < E) atomicAdd(&cnt[col[e]], 1);
}

__global__ void scan_block(const int* __restrict__ cnt, int* __restrict__ incl,
                           int* __restrict__ bsum, int N) {
    __shared__ int s[1024];
    int tid = threadIdx.x;
    int i = blockIdx.x * 1024 + tid;
    int v = (i < N) ? cnt[i] : 0;
    s[tid] = v;
    __syncthreads();
    for (int off = 1; off < 1024; off <<= 1) {
        int t = (tid >= off) ? s[tid - off] : 0;
        __syncthreads();
        s[tid] += t;
        __syncthreads();
    }
    if (i < N) incl[i] = s[tid];
    if (tid == 1023) bsum[blockIdx.x] = s[1023];
}

__global__ void scan_partials(const int* __restrict__ bsum, int* __restrict__ boff, int nb) {
    __shared__ int s[1024];
    int tid = threadIdx.x;
    int v = (tid < nb) ? bsum[tid] : 0;
    s[tid] = v;
    __syncthreads();
    for (int off = 1; off < 1024; off <<= 1) {
        int t = (tid >= off) ? s[tid - off] : 0;
        __syncthreads();
        s[tid] += t;
        __syncthreads();
    }
    if (tid < nb) boff[tid] = s[tid] - v;  // exclusive
}

__global__ void finalize_csr(const int* __restrict__ cnt, const int* __restrict__ incl,
                             const int* __restrict__ boff, int* __restrict__ ptr,
                             int* __restrict__ fill, float* __restrict__ dinv, int N) {
    int i = blockIdx.x * blockDim.x + threadIdx.x;
    if (i >= N) return;
    int excl = incl[i] - cnt[i] + boff[i >> 10];
    ptr[i] = excl;
    fill[i] = excl;
    dinv[i] = rsqrtf((float)(cnt[i] + 1));  // +1 self loop -> deg>0 always
    if (i == N - 1) ptr[N] = excl + cnt[i];
}

__global__ void fill_csr(const int* __restrict__ row, const int* __restrict__ col,
                         int* __restrict__ fill, int* __restrict__ srcs, int E) {
    int e = blockIdx.x * blockDim.x + threadIdx.x;
    if (e >= E) return;
    int p = atomicAdd(&fill[col[e]], 1);
    srcs[p] = row[e];
}

// ---- Aggregation: AG[v] = dinv[v]*( dinv[v]*H[v] + sum_e dinv[src]*H[src] ) -
// One wave per node, lane = feature. Per 64-edge chunk: coalesced index load +
// L2-resident dinv gather, then shfl-broadcast with 8-wide unrolled gathers.

__global__ void __launch_bounds__(256) aggregate(const bf16* __restrict__ Hin,
                                                 const int* __restrict__ ptr,
                                                 const int* __restrict__ srcs,
                                                 const float* __restrict__ dinv,
                                                 bf16* __restrict__ AG, int N) {
    int t = blockIdx.x * blockDim.x + threadIdx.x;
    int v = t >> 6;
    int lane = t & 63;
    if (v >= N) return;
    int beg = ptr[v], end = ptr[v + 1];
    float dv = dinv[v];
    float acc = dv * b2f(Hin[(size_t)v * DDIM + lane]);  // self loop (x dv again below)
    for (int base = beg; base < end; base += 64) {
        int m = end - base;
        if (m > 64) m = 64;
        int  sidx = (base + lane < end) ? srcs[base + lane] : 0;  // coalesced
        float wln = (base + lane < end) ? dinv[sidx] : 0.f;       // L2-resident gather
        int j = 0;
        for (; j + 8 <= m; j += 8) {
            float p0 = 0.f, p1 = 0.f;
#pragma unroll
            for (int u = 0; u < 8; u += 2) {
                int   s0 = __shfl(sidx, j + u, 64);
                float w0 = __shfl(wln, j + u, 64);
                int   s1 = __shfl(sidx, j + u + 1, 64);
                float w1 = __shfl(wln, j + u + 1, 64);
                float h0 = b2f(Hin[(size_t)s0 * DDIM + lane]);  // independent gathers
                float h1 = b2f(Hin[(size_t)s1 * DDIM + lane]);
                p0 += w0 * h0;
                p1 += w1 * h1;
            }
            acc += p0 + p1;
        }
        for (; j < m; j++) {
            int   s = __shfl(sidx, j, 64);
            float w = __shfl(wln, j, 64);
            acc += w * b2f(Hin[(size_t)s * DDIM + lane]);
        }
    }
    AG[(size_t)v * DDIM + lane] = __float2bfloat16(dv * acc);
}

// ---- Fused GEMM (AG @ W + b) + LayerNorm (+ReLU) ---------------------------
// One block = 16 rows; one wave = 4 rows x 64 cols (lane = col).

__global__ void __launch_bounds__(256) gemm_ln(const bf16* __restrict__ AG,
                                               const bf16* __restrict__ W,
                                               const bf16* __restrict__ bias,
                                               const bf16* __restrict__ gamma,
                                               const bf16* __restrict__ beta,
                                               bf16* __restrict__ outB,
                                               float* __restrict__ outF,
                                               const int* __restrict__ flagF32,
                                               int relu, int last) {
    __shared__ float Ws[4096];  // W[k][j] row-major, 16 KB
    __shared__ float As[1024];  // 16 rows x 64
    int tid = threadIdx.x;
    const ushort4* wp = (const ushort4*)W;  // 4096 bf16 = 1024 x ushort4
    for (int i = tid; i < 1024; i += 256) {
        ushort4 u = wp[i];
        Ws[i * 4 + 0] = bits2f(u.x);
        Ws[i * 4 + 1] = bits2f(u.y);
        Ws[i * 4 + 2] = bits2f(u.z);
        Ws[i * 4 + 3] = bits2f(u.w);
    }
    {
        const ushort4* ap = (const ushort4*)(AG + (size_t)blockIdx.x * 1024);
        ushort4 u = ap[tid];  // 256 threads x 4 = 1024 elements
        As[tid * 4 + 0] = bits2f(u.x);
        As[tid * 4 + 1] = bits2f(u.y);
        As[tid * 4 + 2] = bits2f(u.z);
        As[tid * 4 + 3] = bits2f(u.w);
    }
    __syncthreads();

    int lane = tid & 63;
    int wv = tid >> 6;
    int l0 = wv * 4;
    float a0 = 0.f, a1 = 0.f, a2 = 0.f, a3 = 0.f;
#pragma unroll 8
    for (int k = 0; k < 64; k++) {
        float w = Ws[k * 64 + lane];      // 2 lanes/bank: free
        a0 += As[(l0 + 0) * 64 + k] * w;  // broadcast
        a1 += As[(l0 + 1) * 64 + k] * w;
        a2 += As[(l0 + 2) * 64 + k] * w;
        a3 += As[(l0 + 3) * 64 + k] * w;
    }
    float bb = b2f(bias[lane]);
    float gg = b2f(gamma[lane]);
    float be = b2f(beta[lane]);
    int f32o = last ? flagF32[0] : 0;  // wave-uniform
    size_t n0 = (size_t)blockIdx.x * 16 + l0;
    float accs[4] = {a0, a1, a2, a3};
#pragma unroll
    for (int i = 0; i < 4; i++) {
        float vv = accs[i] + bb;
        float sum = vv;
#pragma unroll
        for (int m = 1; m < 64; m <<= 1) sum += __shfl_xor(sum, m, 64);
        float mu = sum * (1.f / 64.f);
        float d = vv - mu;
        float sq = d * d;
#pragma unroll
        for (int m = 1; m < 64; m <<= 1) sq += __shfl_xor(sq, m, 64);
        float var = sq * (1.f / 64.f);
        float o = d * rsqrtf(var + EPSV) * gg + be;
        if (relu) o = fmaxf(o, 0.f);
        size_t idx = (n0 + i) * DDIM + lane;
        if (f32o) outF[idx] = o;
        else      outB[idx] = __float2bfloat16(o);
    }
}

// ---- Launch ----------------------------------------------------------------

extern "C" void kernel_launch(void* const* d_in, const int* in_sizes, int n_in,
                              void* d_out, int out_size, void* d_ws, size_t ws_size,
                              hipStream_t stream) {
    (void)n_in; (void)out_size; (void)ws_size;
    const void* x      = d_in[0];
    const void* Wsrc   = d_in[1];
    const void* bsrc   = d_in[2];
    const void* gsrc   = d_in[3];
    const void* btsrc  = d_in[4];
    const int*  ei     = (const int*)d_in[5];
    int N = in_sizes[0] / DDIM;   // 100000
    int E = in_sizes[5] / 2;      // 1600000
    const int* rowp = ei;         // sources (gather)
    const int* colp = ei + E;     // targets (scatter)

    // workspace carve-out (256B aligned); peak ~33 MB
    char* w = (char*)d_ws;
    auto alloc = [&](size_t bytes) -> char* {
        char* p = w;
        w += (bytes + 255) / 256 * 256;
        return p;
    };
    int*   flag = (int*)alloc(4);
    int*   ptr  = (int*)alloc((size_t)(N + 1) * 4);
    int*   srcs = (int*)alloc((size_t)E * 4);
    float* dinv = (float*)alloc((size_t)N * 4);
    bf16*  H    = (bf16*)alloc((size_t)N * DDIM * 2);
    bf16*  wsW  = (bf16*)alloc((size_t)3 * 4096 * 2);
    bf16*  wsB  = (bf16*)alloc(192 * 2);
    bf16*  wsG  = (bf16*)alloc(192 * 2);
    bf16*  wsBt = (bf16*)alloc(192 * 2);
    char*  agreg = alloc((size_t)N * DDIM * 2);
    bf16*  AG   = (bf16*)agreg;
    // CSR-build temporaries aliased into AG region (dead before AG is written)
    int*   cnt  = (int*)agreg;
    int*   incl = cnt + N;
    int*   fill = incl + N;
    int*   bsum = fill + N;
    int*   boff = bsum + 1024;

    const int tb = 256;
    detect_dtype<<<1, 64, 0, stream>>>((const u32*)gsrc, flag);
    hipMemsetAsync(cnt, 0, (size_t)N * 4, stream);
    count_deg<<<(E + tb - 1) / tb, tb, 0, stream>>>(colp, cnt, E);
    int nb = (N + 1023) / 1024;  // 98
    scan_block<<<nb, 1024, 0, stream>>>(cnt, incl, bsum, N);
    scan_partials<<<1, 1024, 0, stream>>>(bsum, boff, nb);
    finalize_csr<<<(N + tb - 1) / tb, tb, 0, stream>>>(cnt, incl, boff, ptr, fill, dinv, N);
    fill_csr<<<(E + tb - 1) / tb, tb, 0, stream>>>(rowp, colp, fill, srcs, E);

    // normalize inputs to bf16 (no-op copy if already bf16)
    convert_to_bf16<<<(N * DDIM + tb - 1) / tb, tb, 0, stream>>>(x, H, flag, N * DDIM);
    int nPar = 3 * 4096 + 3 * 192;
    convert_params<<<(nPar + tb - 1) / tb, tb, 0, stream>>>(Wsrc, bsrc, gsrc, btsrc,
                                                            wsW, wsB, wsG, wsBt,
                                                            flag, 3 * 4096, 192);

    int aggBlocks = (N * DDIM + tb - 1) / tb;  // one wave per node
    int gBlocks = N / 16;                      // 6250

    aggregate<<<aggBlocks, tb, 0, stream>>>(H, ptr, srcs, dinv, AG, N);
    gemm_ln<<<gBlocks, tb, 0, stream>>>(AG, wsW + 0 * 4096, wsB + 0,   wsG + 0,   wsBt + 0,   H, nullptr, flag, 1, 0);
    aggregate<<<aggBlocks, tb, 0, stream>>>(H, ptr, srcs, dinv, AG, N);
    gemm_ln<<<gBlocks, tb, 0, stream>>>(AG, wsW + 1 * 4096, wsB + 64,  wsG + 64,  wsBt + 64,  H, nullptr, flag, 1, 0);
    aggregate<<<aggBlocks, tb, 0, stream>>>(H, ptr, srcs, dinv, AG, N);
    gemm_ln<<<gBlocks, tb, 0, stream>>>(AG, wsW + 2 * 4096, wsB + 128, wsG + 128, wsBt + 128,
                                        (bf16*)d_out, (float*)d_out, flag, 0, 1);
}

// Round 4
// 488.163 us; speedup vs baseline: 1.7411x; 1.1915x over previous
//
#include <hip/hip_runtime.h>
#include <hip/hip_bf16.h>

// 3-layer GCN, N=100000, E=1.6M, D=64.
// Restructure: LN(Agg(h) @ W + b) per layer (aggregation commutes with @W).
// CSR build v2: bucket-partition edges by col>>9 into their final CSR spans
// (coalesced LDS-staged runs), then per-bucket local scatter (32 KB window)
// -> kills the 16x partial-line write amplification seen in fill_csr (R3:
// WRITE_SIZE 105 MB for a 6.4 MB array).

#define DDIM 64
#define EPSV 1e-5f
#define BSHIFT 9           // 512 nodes per bucket
#define BNODES (1 << BSHIFT)
#define NBUCK 256          // >= ceil(N/512)=196
#define CHUNK 4096         // edges per partition block

typedef __hip_bfloat16 bf16;
typedef unsigned int u32;
typedef unsigned short u16;
typedef unsigned long long u64;

__device__ __forceinline__ float b2f(bf16 v) { return __bfloat162float(v); }
__device__ __forceinline__ float bits2f(u16 b) {
    union { u32 u; float f; } c; c.u = ((u32)b) << 16; return c.f;
}
__device__ __forceinline__ float cvt_load(const void* src, int i, int f32) {
    return f32 ? ((const float*)src)[i] : b2f(((const bf16*)src)[i]);
}

// ---- dtype detect: gammas are all ones; word0 = 0x3F803F80 (bf16) or 0x3F800000 (f32)
__global__ void detect_dtype(const u32* __restrict__ g, int* __restrict__ flagF32) {
    if (threadIdx.x == 0 && blockIdx.x == 0) *flagF32 = (g[0] == 0x3F800000u) ? 1 : 0;
}

__global__ void convert_to_bf16(const void* __restrict__ src, bf16* __restrict__ dst,
                                const int* __restrict__ flagF32, int n) {
    int i = blockIdx.x * blockDim.x + threadIdx.x;
    if (i >= n) return;
    dst[i] = __float2bfloat16(cvt_load(src, i, *flagF32));
}

__global__ void convert_params(const void* __restrict__ W, const void* __restrict__ b,
                               const void* __restrict__ g, const void* __restrict__ bt,
                               bf16* __restrict__ dW, bf16* __restrict__ db,
                               bf16* __restrict__ dg, bf16* __restrict__ dbt,
                               const int* __restrict__ flagF32, int nW, int nS) {
    int i = blockIdx.x * blockDim.x + threadIdx.x;
    int f = *flagF32;
    if (i < nW) { dW[i] = __float2bfloat16(cvt_load(W, i, f)); return; }
    i -= nW;
    if (i < nS) { db[i] = __float2bfloat16(cvt_load(b, i, f)); return; }
    i -= nS;
    if (i < nS) { dg[i] = __float2bfloat16(cvt_load(g, i, f)); return; }
    i -= nS;
    if (i < nS) { dbt[i] = __float2bfloat16(cvt_load(bt, i, f)); }
}

// ---- CSR build -------------------------------------------------------------

__global__ void count_deg(const int* __restrict__ col, int* __restrict__ cnt, int E) {
    int e = blockIdx.x * blockDim.x + threadIdx.x;
    if (e < E) atomicAdd(&cnt[col[e]], 1);
}

__global__ void scan_block(const int* __restrict__ cnt, int* __restrict__ incl,
                           int* __restrict__ bsum, int N) {
    __shared__ int s[1024];
    int tid = threadIdx.x;
    int i = blockIdx.x * 1024 + tid;
    int v = (i < N) ? cnt[i] : 0;
    s[tid] = v;
    __syncthreads();
    for (int off = 1; off < 1024; off <<= 1) {
        int t = (tid >= off) ? s[tid - off] : 0;
        __syncthreads();
        s[tid] += t;
        __syncthreads();
    }
    if (i < N) incl[i] = s[tid];
    if (tid == 1023) bsum[blockIdx.x] = s[1023];
}

__global__ void scan_partials(const int* __restrict__ bsum, int* __restrict__ boff, int nb) {
    __shared__ int s[1024];
    int tid = threadIdx.x;
    int v = (tid < nb) ? bsum[tid] : 0;
    s[tid] = v;
    __syncthreads();
    for (int off = 1; off < 1024; off <<= 1) {
        int t = (tid >= off) ? s[tid - off] : 0;
        __syncthreads();
        s[tid] += t;
        __syncthreads();
    }
    if (tid < nb) boff[tid] = s[tid] - v;  // exclusive
}

__global__ void finalize_csr(const int* __restrict__ cnt, const int* __restrict__ incl,
                             const int* __restrict__ boff, int* __restrict__ ptr,
                             int* __restrict__ gcur, float* __restrict__ dinv, int N) {
    int i = blockIdx.x * blockDim.x + threadIdx.x;
    if (i >= N) return;
    int excl = incl[i] - cnt[i] + boff[i >> 10];
    ptr[i] = excl;
    if ((i & (BNODES - 1)) == 0) gcur[i >> BSHIFT] = excl;  // bucket cursor seed
    dinv[i] = rsqrtf((float)(cnt[i] + 1));  // +1 self loop -> deg>0 always
    if (i == N - 1) ptr[N] = excl + cnt[i];
}

// Phase A: partition (row,col) pairs into bucket spans of the CSR (coalesced,
// LDS-staged counting sort per 4096-edge chunk).
__global__ void __launch_bounds__(256) partition_edges(const int* __restrict__ row,
                                                       const int* __restrict__ col,
                                                       int* __restrict__ gcur,
                                                       u64* __restrict__ pairs, int E) {
    __shared__ int hist[NBUCK];
    __shared__ int lbase[NBUCK];
    __shared__ int gdelta[NBUCK];
    __shared__ int lcur[NBUCK];
    __shared__ int sbuf[NBUCK];
    __shared__ int dest[CHUNK];
    __shared__ u64 stage[CHUNK];
    int tid = threadIdx.x;
    int chunk0 = blockIdx.x * CHUNK;
    hist[tid] = 0;
    lcur[tid] = 0;
    __syncthreads();
    int r[16], c[16];
#pragma unroll
    for (int i = 0; i < 16; i++) {
        int idx = chunk0 + i * 256 + tid;
        if (idx < E) {
            r[i] = row[idx];
            c[i] = col[idx];
            atomicAdd(&hist[c[i] >> BSHIFT], 1);
        }
    }
    __syncthreads();
    int h = hist[tid];
    sbuf[tid] = h;
    __syncthreads();
    for (int off = 1; off < 256; off <<= 1) {
        int t = (tid >= off) ? sbuf[tid - off] : 0;
        __syncthreads();
        sbuf[tid] += t;
        __syncthreads();
    }
    int excl = sbuf[tid] - h;
    lbase[tid] = excl;
    int gb = (h > 0) ? atomicAdd(&gcur[tid], h) : 0;
    gdelta[tid] = gb - excl;
    __syncthreads();
#pragma unroll
    for (int i = 0; i < 16; i++) {
        int idx = chunk0 + i * 256 + tid;
        if (idx < E) {
            int b = c[i] >> BSHIFT;
            int pos = lbase[b] + atomicAdd(&lcur[b], 1);
            stage[pos] = ((u64)(u32)c[i] << 32) | (u32)r[i];
            dest[pos] = gdelta[b];
        }
    }
    __syncthreads();
    int chunkN = min(CHUNK, E - chunk0);
    for (int j = tid; j < chunkN; j += 256)
        pairs[(size_t)(dest[j] + j)] = stage[j];  // bucket-contiguous runs
}

// Phase B: per bucket, exact CSR ordering; scatter confined to ~32KB window.
__global__ void __launch_bounds__(512) build_csr(const u64* __restrict__ pairs,
                                                 const int* __restrict__ ptr,
                                                 int* __restrict__ srcs, int N) {
    int node0 = blockIdx.x << BSHIFT;
    int node1 = min(node0 + BNODES, N);
    __shared__ int lptr[BNODES];
    __shared__ int lfill[BNODES];
    int tid = threadIdx.x;
    int nn = node1 - node0;
    if (tid < nn) {
        lptr[tid] = ptr[node0 + tid];
        lfill[tid] = 0;
    }
    __syncthreads();
    int beg = ptr[node0];
    int end = ptr[node1];
    for (int i = beg + tid; i < end; i += 512) {
        u64 pr = pairs[i];
        int cc = (int)(pr >> 32);
        int rr = (int)(pr & 0xffffffffu);
        int li = cc - node0;
        int p = lptr[li] + atomicAdd(&lfill[li], 1);
        srcs[p] = rr;
    }
}

// ---- Aggregation: AG[v] = dinv[v]*( dinv[v]*H[v] + sum_e dinv[src]*H[src] ) -
// One wave per node, lane = feature. Per 64-edge chunk: coalesced index load +
// L2-resident dinv gather, then shfl-broadcast with 8-wide unrolled gathers.

__global__ void __launch_bounds__(256) aggregate(const bf16* __restrict__ Hin,
                                                 const int* __restrict__ ptr,
                                                 const int* __restrict__ srcs,
                                                 const float* __restrict__ dinv,
                                                 bf16* __restrict__ AG, int N) {
    int t = blockIdx.x * blockDim.x + threadIdx.x;
    int v = t >> 6;
    int lane = t & 63;
    if (v >= N) return;
    int beg = ptr[v], end = ptr[v + 1];
    float dv = dinv[v];
    float acc = dv * b2f(Hin[(size_t)v * DDIM + lane]);  // self loop (x dv again below)
    for (int base = beg; base < end; base += 64) {
        int m = end - base;
        if (m > 64) m = 64;
        int  sidx = (base + lane < end) ? srcs[base + lane] : 0;  // coalesced
        float wln = (base + lane < end) ? dinv[sidx] : 0.f;       // L2-resident gather
        int j = 0;
        for (; j + 8 <= m; j += 8) {
            float p0 = 0.f, p1 = 0.f;
#pragma unroll
            for (int u = 0; u < 8; u += 2) {
                int   s0 = __shfl(sidx, j + u, 64);
                float w0 = __shfl(wln, j + u, 64);
                int   s1 = __shfl(sidx, j + u + 1, 64);
                float w1 = __shfl(wln, j + u + 1, 64);
                float h0 = b2f(Hin[(size_t)s0 * DDIM + lane]);  // independent gathers
                float h1 = b2f(Hin[(size_t)s1 * DDIM + lane]);
                p0 += w0 * h0;
                p1 += w1 * h1;
            }
            acc += p0 + p1;
        }
        for (; j < m; j++) {
            int   s = __shfl(sidx, j, 64);
            float w = __shfl(wln, j, 64);
            acc += w * b2f(Hin[(size_t)s * DDIM + lane]);
        }
    }
    AG[(size_t)v * DDIM + lane] = __float2bfloat16(dv * acc);
}

// ---- Fused GEMM (AG @ W + b) + LayerNorm (+ReLU) ---------------------------
// One block = 16 rows; one wave = 4 rows x 64 cols (lane = col).

__global__ void __launch_bounds__(256) gemm_ln(const bf16* __restrict__ AG,
                                               const bf16* __restrict__ W,
                                               const bf16* __restrict__ bias,
                                               const bf16* __restrict__ gamma,
                                               const bf16* __restrict__ beta,
                                               bf16* __restrict__ outB,
                                               float* __restrict__ outF,
                                               const int* __restrict__ flagF32,
                                               int relu, int last) {
    __shared__ float Ws[4096];  // W[k][j] row-major, 16 KB
    __shared__ float As[1024];  // 16 rows x 64
    int tid = threadIdx.x;
    const ushort4* wp = (const ushort4*)W;  // 4096 bf16 = 1024 x ushort4
    for (int i = tid; i < 1024; i += 256) {
        ushort4 u = wp[i];
        Ws[i * 4 + 0] = bits2f(u.x);
        Ws[i * 4 + 1] = bits2f(u.y);
        Ws[i * 4 + 2] = bits2f(u.z);
        Ws[i * 4 + 3] = bits2f(u.w);
    }
    {
        const ushort4* ap = (const ushort4*)(AG + (size_t)blockIdx.x * 1024);
        ushort4 u = ap[tid];  // 256 threads x 4 = 1024 elements
        As[tid * 4 + 0] = bits2f(u.x);
        As[tid * 4 + 1] = bits2f(u.y);
        As[tid * 4 + 2] = bits2f(u.z);
        As[tid * 4 + 3] = bits2f(u.w);
    }
    __syncthreads();

    int lane = tid & 63;
    int wv = tid >> 6;
    int l0 = wv * 4;
    float a0 = 0.f, a1 = 0.f, a2 = 0.f, a3 = 0.f;
#pragma unroll 8
    for (int k = 0; k < 64; k++) {
        float w = Ws[k * 64 + lane];      // 2 lanes/bank: free
        a0 += As[(l0 + 0) * 64 + k] * w;  // broadcast
        a1 += As[(l0 + 1) * 64 + k] * w;
        a2 += As[(l0 + 2) * 64 + k] * w;
        a3 += As[(l0 + 3) * 64 + k] * w;
    }
    float bb = b2f(bias[lane]);
    float gg = b2f(gamma[lane]);
    float be = b2f(beta[lane]);
    int f32o = last ? flagF32[0] : 0;  // wave-uniform
    size_t n0 = (size_t)blockIdx.x * 16 + l0;
    float accs[4] = {a0, a1, a2, a3};
#pragma unroll
    for (int i = 0; i < 4; i++) {
        float vv = accs[i] + bb;
        float sum = vv;
#pragma unroll
        for (int m = 1; m < 64; m <<= 1) sum += __shfl_xor(sum, m, 64);
        float mu = sum * (1.f / 64.f);
        float d = vv - mu;
        float sq = d * d;
#pragma unroll
        for (int m = 1; m < 64; m <<= 1) sq += __shfl_xor(sq, m, 64);
        float var = sq * (1.f / 64.f);
        float o = d * rsqrtf(var + EPSV) * gg + be;
        if (relu) o = fmaxf(o, 0.f);
        size_t idx = (n0 + i) * DDIM + lane;
        if (f32o) outF[idx] = o;
        else      outB[idx] = __float2bfloat16(o);
    }
}

// ---- Launch ----------------------------------------------------------------

extern "C" void kernel_launch(void* const* d_in, const int* in_sizes, int n_in,
                              void* d_out, int out_size, void* d_ws, size_t ws_size,
                              hipStream_t stream) {
    (void)n_in; (void)out_size; (void)ws_size;
    const void* x      = d_in[0];
    const void* Wsrc   = d_in[1];
    const void* bsrc   = d_in[2];
    const void* gsrc   = d_in[3];
    const void* btsrc  = d_in[4];
    const int*  ei     = (const int*)d_in[5];
    int N = in_sizes[0] / DDIM;   // 100000
    int E = in_sizes[5] / 2;      // 1600000
    const int* rowp = ei;         // sources (gather)
    const int* colp = ei + E;     // targets (scatter)

    // workspace carve-out (256B aligned); peak ~33 MB
    char* w = (char*)d_ws;
    auto alloc = [&](size_t bytes) -> char* {
        char* p = w;
        w += (bytes + 255) / 256 * 256;
        return p;
    };
    int*   flag = (int*)alloc(4);
    int*   gcur = (int*)alloc(NBUCK * 4);
    int*   ptr  = (int*)alloc((size_t)(N + 1) * 4);
    int*   srcs = (int*)alloc((size_t)E * 4);
    float* dinv = (float*)alloc((size_t)N * 4);
    char*  hreg = alloc((size_t)N * DDIM * 2);
    bf16*  H    = (bf16*)hreg;
    u64*   pairs = (u64*)hreg;  // E*8 == N*64*2 bytes; dead before H written
    bf16*  wsW  = (bf16*)alloc((size_t)3 * 4096 * 2);
    bf16*  wsB  = (bf16*)alloc(192 * 2);
    bf16*  wsG  = (bf16*)alloc(192 * 2);
    bf16*  wsBt = (bf16*)alloc(192 * 2);
    char*  agreg = alloc((size_t)N * DDIM * 2);
    bf16*  AG   = (bf16*)agreg;
    // CSR-build temporaries aliased into AG region (dead before AG is written)
    int*   cnt  = (int*)agreg;
    int*   incl = cnt + N;
    int*   bsum = incl + N;
    int*   boff = bsum + 1024;

    const int tb = 256;
    detect_dtype<<<1, 64, 0, stream>>>((const u32*)gsrc, flag);
    hipMemsetAsync(cnt, 0, (size_t)N * 4, stream);
    count_deg<<<(E + tb - 1) / tb, tb, 0, stream>>>(colp, cnt, E);
    int nb = (N + 1023) / 1024;  // 98
    scan_block<<<nb, 1024, 0, stream>>>(cnt, incl, bsum, N);
    scan_partials<<<1, 1024, 0, stream>>>(bsum, boff, nb);
    finalize_csr<<<(N + tb - 1) / tb, tb, 0, stream>>>(cnt, incl, boff, ptr, gcur, dinv, N);
    partition_edges<<<(E + CHUNK - 1) / CHUNK, tb, 0, stream>>>(rowp, colp, gcur, pairs, E);
    int nbuck = (N + BNODES - 1) >> BSHIFT;  // 196
    build_csr<<<nbuck, 512, 0, stream>>>(pairs, ptr, srcs, N);

    // normalize inputs to bf16 (no-op copy if already bf16); overwrites pairs
    convert_to_bf16<<<(N * DDIM + tb - 1) / tb, tb, 0, stream>>>(x, H, flag, N * DDIM);
    int nPar = 3 * 4096 + 3 * 192;
    convert_params<<<(nPar + tb - 1) / tb, tb, 0, stream>>>(Wsrc, bsrc, gsrc, btsrc,
                                                            wsW, wsB, wsG, wsBt,
                                                            flag, 3 * 4096, 192);

    int aggBlocks = (N * DDIM + tb - 1) / tb;  // one wave per node
    int gBlocks = N / 16;                      // 6250

    aggregate<<<aggBlocks, tb, 0, stream>>>(H, ptr, srcs, dinv, AG, N);
    gemm_ln<<<gBlocks, tb, 0, stream>>>(AG, wsW + 0 * 4096, wsB + 0,   wsG + 0,   wsBt + 0,   H, nullptr, flag, 1, 0);
    aggregate<<<aggBlocks, tb, 0, stream>>>(H, ptr, srcs, dinv, AG, N);
    gemm_ln<<<gBlocks, tb, 0, stream>>>(AG, wsW + 1 * 4096, wsB + 64,  wsG + 64,  wsBt + 64,  H, nullptr, flag, 1, 0);
    aggregate<<<aggBlocks, tb, 0, stream>>>(H, ptr, srcs, dinv, AG, N);
    gemm_ln<<<gBlocks, tb, 0, stream>>>(AG, wsW + 2 * 4096, wsB + 128, wsG + 128, wsBt + 128,
                                        (bf16*)d_out, (float*)d_out, flag, 0, 1);
}

// Round 5
// 435.203 us; speedup vs baseline: 1.9530x; 1.1217x over previous
//
#include <hip/hip_runtime.h>
#include <hip/hip_bf16.h>

// 3-layer GCN, N=100000, E=1.6M, D=64.
// Restructure: LN(Agg(h) @ W + b) per layer (aggregation commutes with @W).
// CSR build v3: bucket-grained counting (LDS hist + ~196 global atomics/blk)
// -> bucket scan -> partition into final CSR spans -> per-bucket local degree
// histogram + scan + scatter (all LDS / 32KB windows). No global fine-grained
// atomics anywhere (R4: count_deg wrote 50 MB HBM for a 400 KB array).

#define DDIM 64
#define EPSV 1e-5f
#define BSHIFT 9           // 512 nodes per bucket
#define BNODES (1 << BSHIFT)
#define NBUCK 256          // >= ceil(N/512)=196
#define CHUNK 4096         // edges per partition block

typedef __hip_bfloat16 bf16;
typedef unsigned int u32;
typedef unsigned short u16;
typedef unsigned long long u64;

__device__ __forceinline__ float b2f(bf16 v) { return __bfloat162float(v); }
__device__ __forceinline__ float bits2f(u16 b) {
    union { u32 u; float f; } c; c.u = ((u32)b) << 16; return c.f;
}
__device__ __forceinline__ float cvt_load(const void* src, int i, int f32) {
    return f32 ? ((const float*)src)[i] : b2f(((const bf16*)src)[i]);
}

// ---- dtype detect: gammas are all ones; word0 = 0x3F803F80 (bf16) or 0x3F800000 (f32)
__global__ void detect_dtype(const u32* __restrict__ g, int* __restrict__ flagF32) {
    if (threadIdx.x == 0 && blockIdx.x == 0) *flagF32 = (g[0] == 0x3F800000u) ? 1 : 0;
}

__global__ void convert_to_bf16(const void* __restrict__ src, bf16* __restrict__ dst,
                                const int* __restrict__ flagF32, int n) {
    int i = blockIdx.x * blockDim.x + threadIdx.x;
    if (i >= n) return;
    dst[i] = __float2bfloat16(cvt_load(src, i, *flagF32));
}

__global__ void convert_params(const void* __restrict__ W, const void* __restrict__ b,
                               const void* __restrict__ g, const void* __restrict__ bt,
                               bf16* __restrict__ dW, bf16* __restrict__ db,
                               bf16* __restrict__ dg, bf16* __restrict__ dbt,
                               const int* __restrict__ flagF32, int nW, int nS) {
    int i = blockIdx.x * blockDim.x + threadIdx.x;
    int f = *flagF32;
    if (i < nW) { dW[i] = __float2bfloat16(cvt_load(W, i, f)); return; }
    i -= nW;
    if (i < nS) { db[i] = __float2bfloat16(cvt_load(b, i, f)); return; }
    i -= nS;
    if (i < nS) { dg[i] = __float2bfloat16(cvt_load(g, i, f)); return; }
    i -= nS;
    if (i < nS) { dbt[i] = __float2bfloat16(cvt_load(bt, i, f)); }
}

// ---- CSR build -------------------------------------------------------------

// Coarse bucket histogram: LDS-local, then <=NBUCK global atomics per block.
__global__ void __launch_bounds__(256) bucket_count(const int* __restrict__ col,
                                                    int* __restrict__ bcnt, int E) {
    __shared__ int h[NBUCK];
    int tid = threadIdx.x;
    h[tid] = 0;
    __syncthreads();
    for (int i = blockIdx.x * blockDim.x + tid; i < E; i += gridDim.x * blockDim.x)
        atomicAdd(&h[col[i] >> BSHIFT], 1);
    __syncthreads();
    int v = h[tid];
    if (v) atomicAdd(&bcnt[tid], v);
}

// Scan bucket totals -> span starts (bbase) + partition cursors (gcur).
__global__ void bucket_scan(const int* __restrict__ bcnt, int* __restrict__ bbase,
                            int* __restrict__ gcur, int nbuck, int E) {
    __shared__ int s[NBUCK];
    int tid = threadIdx.x;
    int v = (tid < nbuck) ? bcnt[tid] : 0;
    s[tid] = v;
    __syncthreads();
    for (int off = 1; off < NBUCK; off <<= 1) {
        int t = (tid >= off) ? s[tid - off] : 0;
        __syncthreads();
        s[tid] += t;
        __syncthreads();
    }
    int excl = s[tid] - v;
    if (tid < nbuck) { bbase[tid] = excl; gcur[tid] = excl; }
    if (tid == 0) bbase[nbuck] = E;
}

// Phase A: partition (row,col) pairs into bucket spans of the CSR (coalesced,
// LDS-staged counting sort per 4096-edge chunk).
__global__ void __launch_bounds__(256) partition_edges(const int* __restrict__ row,
                                                       const int* __restrict__ col,
                                                       int* __restrict__ gcur,
                                                       u64* __restrict__ pairs, int E) {
    __shared__ int hist[NBUCK];
    __shared__ int lbase[NBUCK];
    __shared__ int gdelta[NBUCK];
    __shared__ int lcur[NBUCK];
    __shared__ int sbuf[NBUCK];
    __shared__ int dest[CHUNK];
    __shared__ u64 stage[CHUNK];
    int tid = threadIdx.x;
    int chunk0 = blockIdx.x * CHUNK;
    hist[tid] = 0;
    lcur[tid] = 0;
    __syncthreads();
    int r[16], c[16];
#pragma unroll
    for (int i = 0; i < 16; i++) {
        int idx = chunk0 + i * 256 + tid;
        if (idx < E) {
            r[i] = row[idx];
            c[i] = col[idx];
            atomicAdd(&hist[c[i] >> BSHIFT], 1);
        }
    }
    __syncthreads();
    int h = hist[tid];
    sbuf[tid] = h;
    __syncthreads();
    for (int off = 1; off < 256; off <<= 1) {
        int t = (tid >= off) ? sbuf[tid - off] : 0;
        __syncthreads();
        sbuf[tid] += t;
        __syncthreads();
    }
    int excl = sbuf[tid] - h;
    lbase[tid] = excl;
    int gb = (h > 0) ? atomicAdd(&gcur[tid], h) : 0;
    gdelta[tid] = gb - excl;
    __syncthreads();
#pragma unroll
    for (int i = 0; i < 16; i++) {
        int idx = chunk0 + i * 256 + tid;
        if (idx < E) {
            int b = c[i] >> BSHIFT;
            int pos = lbase[b] + atomicAdd(&lcur[b], 1);
            stage[pos] = ((u64)(u32)c[i] << 32) | (u32)r[i];
            dest[pos] = gdelta[b];
        }
    }
    __syncthreads();
    int chunkN = min(CHUNK, E - chunk0);
    for (int j = tid; j < chunkN; j += 256)
        pairs[(size_t)(dest[j] + j)] = stage[j];  // bucket-contiguous runs
}

// Phase B: per bucket: local degree histogram -> LDS scan -> ptr/dinv write ->
// local scatter of srcs (confined ~32KB window).
__global__ void __launch_bounds__(512) build_csr(const u64* __restrict__ pairs,
                                                 const int* __restrict__ bbase,
                                                 int* __restrict__ ptr,
                                                 int* __restrict__ srcs,
                                                 float* __restrict__ dinv,
                                                 int N, int E) {
    __shared__ int deg[BNODES];
    __shared__ int lptr[BNODES];
    __shared__ int lfill[BNODES];
    int b = blockIdx.x;
    int node0 = b << BSHIFT;
    int nn = min(BNODES, N - node0);
    int tid = threadIdx.x;
    deg[tid] = 0;
    lfill[tid] = 0;
    __syncthreads();
    int beg = bbase[b], end = bbase[b + 1];
    for (int i = beg + tid; i < end; i += 512)
        atomicAdd(&deg[(int)(pairs[i] >> 32) - node0], 1);
    __syncthreads();
    int d = deg[tid];
    lptr[tid] = d;
    __syncthreads();
    for (int off = 1; off < BNODES; off <<= 1) {
        int t = (tid >= off) ? lptr[tid - off] : 0;
        __syncthreads();
        lptr[tid] += t;
        __syncthreads();
    }
    int excl = lptr[tid] - d;   // own slot only
    lptr[tid] = beg + excl;     // own slot only
    if (tid < nn) {
        ptr[node0 + tid] = beg + excl;
        dinv[node0 + tid] = rsqrtf((float)(d + 1));  // +1 self loop -> deg>0
    }
    if (b == 0 && tid == 0) ptr[N] = E;
    __syncthreads();
    for (int i = beg + tid; i < end; i += 512) {
        u64 pr = pairs[i];
        int li = (int)(pr >> 32) - node0;
        int p = lptr[li] + atomicAdd(&lfill[li], 1);
        srcs[p] = (int)(pr & 0xffffffffu);
    }
}

// ---- Aggregation: AG[v] = dinv[v]*( dinv[v]*H[v] + sum_e dinv[src]*H[src] ) -
// One wave per node, lane = feature. Per 64-edge chunk: coalesced index load +
// L2-resident dinv gather, then shfl-broadcast with 8-wide unrolled gathers.

__global__ void __launch_bounds__(256) aggregate(const bf16* __restrict__ Hin,
                                                 const int* __restrict__ ptr,
                                                 const int* __restrict__ srcs,
                                                 const float* __restrict__ dinv,
                                                 bf16* __restrict__ AG, int N) {
    int t = blockIdx.x * blockDim.x + threadIdx.x;
    int v = t >> 6;
    int lane = t & 63;
    if (v >= N) return;
    int beg = ptr[v], end = ptr[v + 1];
    float dv = dinv[v];
    float acc = dv * b2f(Hin[(size_t)v * DDIM + lane]);  // self loop (x dv again below)
    for (int base = beg; base < end; base += 64) {
        int m = end - base;
        if (m > 64) m = 64;
        int  sidx = (base + lane < end) ? srcs[base + lane] : 0;  // coalesced
        float wln = (base + lane < end) ? dinv[sidx] : 0.f;       // L2-resident gather
        int j = 0;
        for (; j + 8 <= m; j += 8) {
            float p0 = 0.f, p1 = 0.f;
#pragma unroll
            for (int u = 0; u < 8; u += 2) {
                int   s0 = __shfl(sidx, j + u, 64);
                float w0 = __shfl(wln, j + u, 64);
                int   s1 = __shfl(sidx, j + u + 1, 64);
                float w1 = __shfl(wln, j + u + 1, 64);
                float h0 = b2f(Hin[(size_t)s0 * DDIM + lane]);  // independent gathers
                float h1 = b2f(Hin[(size_t)s1 * DDIM + lane]);
                p0 += w0 * h0;
                p1 += w1 * h1;
            }
            acc += p0 + p1;
        }
        for (; j < m; j++) {
            int   s = __shfl(sidx, j, 64);
            float w = __shfl(wln, j, 64);
            acc += w * b2f(Hin[(size_t)s * DDIM + lane]);
        }
    }
    AG[(size_t)v * DDIM + lane] = __float2bfloat16(dv * acc);
}

// ---- Fused GEMM (AG @ W + b) + LayerNorm (+ReLU) ---------------------------
// One block = 16 rows; one wave = 4 rows x 64 cols (lane = col).

__global__ void __launch_bounds__(256) gemm_ln(const bf16* __restrict__ AG,
                                               const bf16* __restrict__ W,
                                               const bf16* __restrict__ bias,
                                               const bf16* __restrict__ gamma,
                                               const bf16* __restrict__ beta,
                                               bf16* __restrict__ outB,
                                               float* __restrict__ outF,
                                               const int* __restrict__ flagF32,
                                               int relu, int last) {
    __shared__ float Ws[4096];  // W[k][j] row-major, 16 KB
    __shared__ float As[1024];  // 16 rows x 64
    int tid = threadIdx.x;
    const ushort4* wp = (const ushort4*)W;  // 4096 bf16 = 1024 x ushort4
    for (int i = tid; i < 1024; i += 256) {
        ushort4 u = wp[i];
        Ws[i * 4 + 0] = bits2f(u.x);
        Ws[i * 4 + 1] = bits2f(u.y);
        Ws[i * 4 + 2] = bits2f(u.z);
        Ws[i * 4 + 3] = bits2f(u.w);
    }
    {
        const ushort4* ap = (const ushort4*)(AG + (size_t)blockIdx.x * 1024);
        ushort4 u = ap[tid];  // 256 threads x 4 = 1024 elements
        As[tid * 4 + 0] = bits2f(u.x);
        As[tid * 4 + 1] = bits2f(u.y);
        As[tid * 4 + 2] = bits2f(u.z);
        As[tid * 4 + 3] = bits2f(u.w);
    }
    __syncthreads();

    int lane = tid & 63;
    int wv = tid >> 6;
    int l0 = wv * 4;
    float a0 = 0.f, a1 = 0.f, a2 = 0.f, a3 = 0.f;
#pragma unroll 8
    for (int k = 0; k < 64; k++) {
        float w = Ws[k * 64 + lane];      // 2 lanes/bank: free
        a0 += As[(l0 + 0) * 64 + k] * w;  // broadcast
        a1 += As[(l0 + 1) * 64 + k] * w;
        a2 += As[(l0 + 2) * 64 + k] * w;
        a3 += As[(l0 + 3) * 64 + k] * w;
    }
    float bb = b2f(bias[lane]);
    float gg = b2f(gamma[lane]);
    float be = b2f(beta[lane]);
    int f32o = last ? flagF32[0] : 0;  // wave-uniform
    size_t n0 = (size_t)blockIdx.x * 16 + l0;
    float accs[4] = {a0, a1, a2, a3};
#pragma unroll
    for (int i = 0; i < 4; i++) {
        float vv = accs[i] + bb;
        float sum = vv;
#pragma unroll
        for (int m = 1; m < 64; m <<= 1) sum += __shfl_xor(sum, m, 64);
        float mu = sum * (1.f / 64.f);
        float d = vv - mu;
        float sq = d * d;
#pragma unroll
        for (int m = 1; m < 64; m <<= 1) sq += __shfl_xor(sq, m, 64);
        float var = sq * (1.f / 64.f);
        float o = d * rsqrtf(var + EPSV) * gg + be;
        if (relu) o = fmaxf(o, 0.f);
        size_t idx = (n0 + i) * DDIM + lane;
        if (f32o) outF[idx] = o;
        else      outB[idx] = __float2bfloat16(o);
    }
}

// ---- Launch ----------------------------------------------------------------

extern "C" void kernel_launch(void* const* d_in, const int* in_sizes, int n_in,
                              void* d_out, int out_size, void* d_ws, size_t ws_size,
                              hipStream_t stream) {
    (void)n_in; (void)out_size; (void)ws_size;
    const void* x      = d_in[0];
    const void* Wsrc   = d_in[1];
    const void* bsrc   = d_in[2];
    const void* gsrc   = d_in[3];
    const void* btsrc  = d_in[4];
    const int*  ei     = (const int*)d_in[5];
    int N = in_sizes[0] / DDIM;   // 100000
    int E = in_sizes[5] / 2;      // 1600000
    const int* rowp = ei;         // sources (gather)
    const int* colp = ei + E;     // targets (scatter)

    // workspace carve-out (256B aligned); peak ~33 MB
    char* w = (char*)d_ws;
    auto alloc = [&](size_t bytes) -> char* {
        char* p = w;
        w += (bytes + 255) / 256 * 256;
        return p;
    };
    int*   flag  = (int*)alloc(4);
    int*   gcur  = (int*)alloc(NBUCK * 4);
    int*   bcnt  = (int*)alloc(NBUCK * 4);
    int*   bbase = (int*)alloc((NBUCK + 1) * 4);
    int*   ptr   = (int*)alloc((size_t)(N + 1) * 4);
    int*   srcs  = (int*)alloc((size_t)E * 4);
    float* dinv  = (float*)alloc((size_t)N * 4);
    char*  hreg  = alloc((size_t)N * DDIM * 2);
    bf16*  H     = (bf16*)hreg;
    u64*   pairs = (u64*)hreg;  // E*8 == N*64*2 bytes; dead before H written
    bf16*  wsW   = (bf16*)alloc((size_t)3 * 4096 * 2);
    bf16*  wsB   = (bf16*)alloc(192 * 2);
    bf16*  wsG   = (bf16*)alloc(192 * 2);
    bf16*  wsBt  = (bf16*)alloc(192 * 2);
    bf16*  AG    = (bf16*)alloc((size_t)N * DDIM * 2);

    const int tb = 256;
    int nbuck = (N + BNODES - 1) >> BSHIFT;  // 196
    detect_dtype<<<1, 64, 0, stream>>>((const u32*)gsrc, flag);
    hipMemsetAsync(bcnt, 0, NBUCK * 4, stream);
    bucket_count<<<256, tb, 0, stream>>>(colp, bcnt, E);
    bucket_scan<<<1, NBUCK, 0, stream>>>(bcnt, bbase, gcur, nbuck, E);
    partition_edges<<<(E + CHUNK - 1) / CHUNK, tb, 0, stream>>>(rowp, colp, gcur, pairs, E);
    build_csr<<<nbuck, 512, 0, stream>>>(pairs, bbase, ptr, srcs, dinv, N, E);

    // normalize inputs to bf16 (no-op copy if already bf16); overwrites pairs
    convert_to_bf16<<<(N * DDIM + tb - 1) / tb, tb, 0, stream>>>(x, H, flag, N * DDIM);
    int nPar = 3 * 4096 + 3 * 192;
    convert_params<<<(nPar + tb - 1) / tb, tb, 0, stream>>>(Wsrc, bsrc, gsrc, btsrc,
                                                            wsW, wsB, wsG, wsBt,
                                                            flag, 3 * 4096, 192);

    int aggBlocks = (N * DDIM + tb - 1) / tb;  // one wave per node
    int gBlocks = N / 16;                      // 6250

    aggregate<<<aggBlocks, tb, 0, stream>>>(H, ptr, srcs, dinv, AG, N);
    gemm_ln<<<gBlocks, tb, 0, stream>>>(AG, wsW + 0 * 4096, wsB + 0,   wsG + 0,   wsBt + 0,   H, nullptr, flag, 1, 0);
    aggregate<<<aggBlocks, tb, 0, stream>>>(H, ptr, srcs, dinv, AG, N);
    gemm_ln<<<gBlocks, tb, 0, stream>>>(AG, wsW + 1 * 4096, wsB + 64,  wsG + 64,  wsBt + 64,  H, nullptr, flag, 1, 0);
    aggregate<<<aggBlocks, tb, 0, stream>>>(H, ptr, srcs, dinv, AG, N);
    gemm_ln<<<gBlocks, tb, 0, stream>>>(AG, wsW + 2 * 4096, wsB + 128, wsG + 128, wsBt + 128,
                                        (bf16*)d_out, (float*)d_out, flag, 0, 1);
}